// Round 1
// baseline (1066.938 us; speedup 1.0000x reference)
//
#include <hip/hip_runtime.h>
#include <hip/hip_bf16.h>

typedef __attribute__((ext_vector_type(8))) short bf16x8;
typedef __attribute__((ext_vector_type(4))) float f32x4;

constexpr int BATCH = 32, SEQ = 3136, DIM = 768, NH = 12, HD = 64;
constexpr int M_TOT = BATCH * SEQ;   // 100352
constexpr int QKVC  = 3 * DIM;       // 2304

__device__ __forceinline__ float bf2f(unsigned short u) {
  union { unsigned int i; float f; } x; x.i = ((unsigned int)u) << 16; return x.f;
}
__device__ __forceinline__ unsigned short f2bf(float f) {
  union { float f; unsigned int i; } x; x.f = f;
  unsigned int r = x.i + 0x7FFFu + ((x.i >> 16) & 1u);
  return (unsigned short)(r >> 16);
}
__device__ __forceinline__ unsigned int pack2(float lo, float hi) {
  return (unsigned int)f2bf(lo) | ((unsigned int)f2bf(hi) << 16);
}
__device__ __forceinline__ void gload_lds16(const unsigned short* g, unsigned short* l) {
  __builtin_amdgcn_global_load_lds(
      (const __attribute__((address_space(1))) void*)g,
      (__attribute__((address_space(3))) void*)l, 16, 0, 0);
}

// ---------------- fp32 -> bf16 elementwise ----------------
__global__ void conv_kernel(const float* __restrict__ in, unsigned short* __restrict__ out, long n) {
  long i = ((long)blockIdx.x * blockDim.x + threadIdx.x) * 8;
  long stride = (long)gridDim.x * blockDim.x * 8;
  for (; i < n; i += stride) {
    float4 a = *(const float4*)(in + i);
    float4 b = *(const float4*)(in + i + 4);
    uint4 o;
    o.x = pack2(a.x, a.y); o.y = pack2(a.z, a.w);
    o.z = pack2(b.x, b.y); o.w = pack2(b.z, b.w);
    *(uint4*)(out + i) = o;
  }
}

// ---------------- transpose+convert: w[K][N] fp32 -> wt[N][K] bf16 ----------------
__global__ void transp_kernel(const float* __restrict__ w, unsigned short* __restrict__ wt, int K, int N) {
  __shared__ float tile[32][33];
  int n0 = blockIdx.x * 32, k0 = blockIdx.y * 32;
  int tx = threadIdx.x, ty = threadIdx.y;
  #pragma unroll
  for (int i = 0; i < 32; i += 8)
    tile[ty + i][tx] = w[(size_t)(k0 + ty + i) * N + n0 + tx];
  __syncthreads();
  #pragma unroll
  for (int i = 0; i < 32; i += 8)
    wt[(size_t)(n0 + ty + i) * K + k0 + tx] = f2bf(tile[tx][ty + i]);
}

// ---------------- m97-structure GEMM: C[M][Nld] = A[M][K] * Bt[Nld][K]^T ----------------
// OUTMODE 0: bf16 out, exp() applied to columns < 2*DIM (q,k blocks of qkv)
// OUTMODE 1: fp32 out + bias
template<int OUTMODE>
__global__ void gemm_bt(const unsigned short* __restrict__ A, const unsigned short* __restrict__ Bt,
                        void* __restrict__ Cp, const float* __restrict__ bias,
                        int Nld, int K, int MT) {
  __shared__ unsigned short As[128 * 32];
  __shared__ unsigned short Bs[128 * 32];
  int cpx = gridDim.x >> 3;  // grid % 8 == 0 in all launches
  int wg = (blockIdx.x & 7) * cpx + (blockIdx.x >> 3);
  int mt = wg % MT, nt = wg / MT;
  long m0 = (long)mt * 128; int n0 = nt * 128;
  int t = threadIdx.x, lane = t & 63, wid = t >> 6;
  int wr = (wid >> 1) * 64, wc = (wid & 1) * 64;
  int srowi = lane >> 2, sk = (lane & 3) * 8;
  int ko = (lane >> 4) * 8, fl = lane & 15;
  f32x4 acc[4][4] = {};
  for (int kt = 0; kt < K; kt += 32) {
    __syncthreads();
    #pragma unroll
    for (int ci = 0; ci < 2; ++ci) {
      int chunk = wid * 2 + ci;
      int row = chunk * 16 + srowi;
      gload_lds16(A + (size_t)(m0 + row) * K + kt + sk, As + chunk * 512);
      gload_lds16(Bt + (size_t)(n0 + row) * K + kt + sk, Bs + chunk * 512);
    }
    __syncthreads();
    bf16x8 af[4], bfr[4];
    #pragma unroll
    for (int m = 0; m < 4; ++m) af[m] = *(const bf16x8*)(As + (wr + m * 16 + fl) * 32 + ko);
    #pragma unroll
    for (int n = 0; n < 4; ++n) bfr[n] = *(const bf16x8*)(Bs + (wc + n * 16 + fl) * 32 + ko);
    #pragma unroll
    for (int m = 0; m < 4; ++m)
      #pragma unroll
      for (int n = 0; n < 4; ++n)
        acc[m][n] = __builtin_amdgcn_mfma_f32_16x16x32_bf16(af[m], bfr[n], acc[m][n], 0, 0, 0);
  }
  int r0 = (lane >> 4) * 4;
  bool doexp = (OUTMODE == 0) && (n0 < 2 * DIM);  // whole 128-tile is q/k or v (1536 % 128 == 0)
  #pragma unroll
  for (int m = 0; m < 4; ++m) {
    #pragma unroll
    for (int n = 0; n < 4; ++n) {
      long row = m0 + wr + m * 16 + r0;
      int col = n0 + wc + n * 16 + fl;
      if (OUTMODE == 0) {
        unsigned short* C = (unsigned short*)Cp;
        #pragma unroll
        for (int r = 0; r < 4; ++r) {
          float v = acc[m][n][r];
          C[(size_t)(row + r) * Nld + col] = f2bf(doexp ? __expf(v) : v);
        }
      } else {
        float* C = (float*)Cp;
        float bb = bias[col];
        #pragma unroll
        for (int r = 0; r < 4; ++r)
          C[(size_t)(row + r) * Nld + col] = acc[m][n][r] + bb;
      }
    }
  }
}

// ---------------- context: per (b,h) ctx[c][d] = sum_n ek[n][c] v[n][d] / sum_n ek[n][c] ----------------
// qkv columns: [0,768) = exp(q), [768,1536) = exp(k), [1536,2304) = v  (all bf16)
// output ctxT[bh][d][c] bf16
__global__ void ctx_kernel(const unsigned short* __restrict__ qkv, unsigned short* __restrict__ ctxT) {
  int bh = blockIdx.x;
  int b = bh / NH, h = bh % NH;
  __shared__ unsigned short Et[64 * 40];  // Et[c][n_local], padded stride 40
  __shared__ unsigned short Vt[64 * 40];  // Vt[d][n_local]
  __shared__ float denom[64];
  int t = threadIdx.x, lane = t & 63, w = t >> 6;
  if (t < 64) denom[t] = 0.0f;
  int nl = t >> 3, e0 = (t & 7) * 8;
  int ko = (lane >> 4) * 8, fl = lane & 15;
  size_t base = (size_t)b * SEQ * QKVC + (size_t)h * HD;
  float dp[8] = {};
  f32x4 acc[4] = {};
  for (int c0 = 0; c0 < SEQ; c0 += 32) {
    __syncthreads();
    size_t rb = base + (size_t)(c0 + nl) * QKVC;
    uint4 kvec = *(const uint4*)(qkv + rb + DIM + e0);      // exp(k), already bf16
    uint4 vvec = *(const uint4*)(qkv + rb + 2 * DIM + e0);  // v
    const unsigned short* kp = (const unsigned short*)&kvec;
    const unsigned short* vp = (const unsigned short*)&vvec;
    #pragma unroll
    for (int j = 0; j < 8; ++j) {
      dp[j] += bf2f(kp[j]);
      Et[(e0 + j) * 40 + nl] = kp[j];
      Vt[(e0 + j) * 40 + nl] = vp[j];
    }
    __syncthreads();
    bf16x8 af = *(const bf16x8*)(Et + (w * 16 + fl) * 40 + ko);
    #pragma unroll
    for (int nf = 0; nf < 4; ++nf) {
      bf16x8 bv = *(const bf16x8*)(Vt + (nf * 16 + fl) * 40 + ko);
      acc[nf] = __builtin_amdgcn_mfma_f32_16x16x32_bf16(af, bv, acc[nf], 0, 0, 0);
    }
  }
  #pragma unroll
  for (int j = 0; j < 8; ++j) atomicAdd(&denom[e0 + j], dp[j]);
  __syncthreads();
  int r0 = (lane >> 4) * 4;
  unsigned short* outp = ctxT + (size_t)bh * 4096;
  #pragma unroll
  for (int nf = 0; nf < 4; ++nf)
    #pragma unroll
    for (int r = 0; r < 4; ++r) {
      int c = w * 16 + r0 + r;
      int d = nf * 16 + fl;
      outp[d * 64 + c] = f2bf(acc[nf][r] / denom[c]);
    }
}

// ---------------- PV: out[n][d] = (sum_c eq[n][c] ctx[c][d]) / sum_c eq[n][c] ----------------
__global__ void pv_kernel(const unsigned short* __restrict__ qkv, const unsigned short* __restrict__ ctxT,
                          unsigned short* __restrict__ aout) {
  int bid = blockIdx.x;
  int bh = bid / 49, chunk = bid - bh * 49;
  int b = bh / NH, h = bh % NH;
  int n0 = chunk * 64;
  __shared__ unsigned short P[64 * 80];   // P[n_local][c], padded stride 80
  __shared__ unsigned short CT[64 * 80];  // CT[d][c]
  __shared__ float srow[64];
  int t = threadIdx.x, lane = t & 63, w = t >> 6;
  int ko = (lane >> 4) * 8, fl = lane & 15;
  if (t < 64) srow[t] = 0.0f;
  {
    int d = t >> 2, cq = (t & 3) * 16;
    const uint4* src = (const uint4*)(ctxT + (size_t)bh * 4096 + d * 64 + cq);
    *(uint4*)(CT + d * 80 + cq) = src[0];
    *(uint4*)(CT + d * 80 + cq + 8) = src[1];
  }
  __syncthreads();
  {
    int nl = t >> 2, cq = (t & 3) * 16;
    size_t rb = (size_t)(b * SEQ + n0 + nl) * QKVC + h * HD + cq;  // exp(q) block
    uint4 q0 = *(const uint4*)(qkv + rb);
    uint4 q1 = *(const uint4*)(qkv + rb + 8);
    *(uint4*)(P + nl * 80 + cq) = q0;
    *(uint4*)(P + nl * 80 + cq + 8) = q1;
    const unsigned short* qp0 = (const unsigned short*)&q0;
    const unsigned short* qp1 = (const unsigned short*)&q1;
    float s = 0.0f;
    #pragma unroll
    for (int j = 0; j < 8; ++j) s += bf2f(qp0[j]) + bf2f(qp1[j]);
    atomicAdd(&srow[nl], s);
  }
  __syncthreads();
  f32x4 acc[4] = {};
  #pragma unroll
  for (int kk = 0; kk < 2; ++kk) {
    bf16x8 af = *(const bf16x8*)(P + (w * 16 + fl) * 80 + kk * 32 + ko);
    #pragma unroll
    for (int nf = 0; nf < 4; ++nf) {
      bf16x8 bv = *(const bf16x8*)(CT + (nf * 16 + fl) * 80 + kk * 32 + ko);
      acc[nf] = __builtin_amdgcn_mfma_f32_16x16x32_bf16(af, bv, acc[nf], 0, 0, 0);
    }
  }
  int r0 = (lane >> 4) * 4;
  #pragma unroll
  for (int nf = 0; nf < 4; ++nf)
    #pragma unroll
    for (int r = 0; r < 4; ++r) {
      int nlr = w * 16 + r0 + r;
      int d = nf * 16 + fl;
      float v = acc[nf][r] / srow[nlr];
      aout[(size_t)(b * SEQ + n0 + nlr) * DIM + h * HD + d] = f2bf(v);
    }
}

extern "C" void kernel_launch(void* const* d_in, const int* in_sizes, int n_in,
                              void* d_out, int out_size, void* d_ws, size_t ws_size,
                              hipStream_t stream) {
  const float* x      = (const float*)d_in[0];
  const float* w_qkv  = (const float*)d_in[1];
  const float* w_proj = (const float*)d_in[2];
  const float* b_proj = (const float*)d_in[3];
  char* ws = (char*)d_ws;
  // workspace layout (bytes, all 256-aligned):
  //   [0)              x_bf  154,140,672   (reused later as aout)
  //   [154,140,672)    wt_qkv  3,538,944   (reused later as ctxT: 3,145,728)
  //   [157,679,616)    wt_proj 1,179,648
  //   [158,859,264)    qkv   462,422,016   -> total 621,281,280
  unsigned short* x_bf    = (unsigned short*)(ws);
  unsigned short* wt_qkv  = (unsigned short*)(ws + 154140672);
  unsigned short* wt_proj = (unsigned short*)(ws + 157679616);
  unsigned short* qkv     = (unsigned short*)(ws + 158859264);
  unsigned short* ctxT    = (unsigned short*)(ws + 154140672);  // alias wt_qkv (dead after GEMM1)
  unsigned short* aout    = (unsigned short*)(ws);              // alias x_bf (dead after GEMM1)

  conv_kernel<<<2048, 256, 0, stream>>>(x, x_bf, (long)M_TOT * DIM);
  transp_kernel<<<dim3(QKVC / 32, DIM / 32), dim3(32, 8), 0, stream>>>(w_qkv, wt_qkv, DIM, QKVC);
  transp_kernel<<<dim3(DIM / 32, DIM / 32), dim3(32, 8), 0, stream>>>(w_proj, wt_proj, DIM, DIM);
  gemm_bt<0><<<(M_TOT / 128) * (QKVC / 128), 256, 0, stream>>>(x_bf, wt_qkv, qkv, nullptr,
                                                               QKVC, DIM, M_TOT / 128);
  ctx_kernel<<<BATCH * NH, 256, 0, stream>>>(qkv, ctxT);
  pv_kernel<<<BATCH * NH * (SEQ / 64), 256, 0, stream>>>(qkv, ctxT, aout);
  gemm_bt<1><<<(M_TOT / 128) * (DIM / 128), 256, 0, stream>>>(aout, wt_proj, (float*)d_out, b_proj,
                                                              DIM, DIM, M_TOT / 128);
}

// Round 2
// 867.131 us; speedup vs baseline: 1.2304x; 1.2304x over previous
//
#include <hip/hip_runtime.h>
#include <hip/hip_bf16.h>

typedef __attribute__((ext_vector_type(8))) short bf16x8;
typedef __attribute__((ext_vector_type(4))) float f32x4;

constexpr int BATCH = 32, SEQ = 3136, DIM = 768, NH = 12, HD = 64;
constexpr int M_TOT = BATCH * SEQ;   // 100352
constexpr int QKVC  = 3 * DIM;       // 2304
constexpr int GK    = 768;           // K for both GEMMs
constexpr int NKT   = GK / 64;       // 12 K-tiles

__device__ __forceinline__ float bf2f(unsigned short u) {
  union { unsigned int i; float f; } x; x.i = ((unsigned int)u) << 16; return x.f;
}
__device__ __forceinline__ unsigned short f2bf(float f) {
  union { float f; unsigned int i; } x; x.f = f;
  unsigned int r = x.i + 0x7FFFu + ((x.i >> 16) & 1u);
  return (unsigned short)(r >> 16);
}
__device__ __forceinline__ unsigned int pack2(float lo, float hi) {
  return (unsigned int)f2bf(lo) | ((unsigned int)f2bf(hi) << 16);
}
__device__ __forceinline__ void gload_lds16(const unsigned short* g, unsigned short* l) {
  __builtin_amdgcn_global_load_lds(
      (const __attribute__((address_space(1))) void*)g,
      (__attribute__((address_space(3))) void*)l, 16, 0, 0);
}

#define BARX()  asm volatile("s_barrier" ::: "memory")
#define LGKM0() asm volatile("s_waitcnt lgkmcnt(0)" ::: "memory")
#define VM8()   asm volatile("s_waitcnt vmcnt(8)" ::: "memory")
#define VM4()   asm volatile("s_waitcnt vmcnt(4)" ::: "memory")
#define VM0()   asm volatile("s_waitcnt vmcnt(0)" ::: "memory")
#define SB0()   __builtin_amdgcn_sched_barrier(0)

// ---------------- fp32 -> bf16 elementwise ----------------
__global__ void conv_kernel(const float* __restrict__ in, unsigned short* __restrict__ out, long n) {
  long i = ((long)blockIdx.x * blockDim.x + threadIdx.x) * 8;
  long stride = (long)gridDim.x * blockDim.x * 8;
  for (; i < n; i += stride) {
    float4 a = *(const float4*)(in + i);
    float4 b = *(const float4*)(in + i + 4);
    uint4 o;
    o.x = pack2(a.x, a.y); o.y = pack2(a.z, a.w);
    o.z = pack2(b.x, b.y); o.w = pack2(b.z, b.w);
    *(uint4*)(out + i) = o;
  }
}

// ---------------- transpose+convert: w[K][N] fp32 -> wt[N][K] bf16 ----------------
__global__ void transp_kernel(const float* __restrict__ w, unsigned short* __restrict__ wt, int K, int N) {
  __shared__ float tile[32][33];
  int n0 = blockIdx.x * 32, k0 = blockIdx.y * 32;
  int tx = threadIdx.x, ty = threadIdx.y;
  #pragma unroll
  for (int i = 0; i < 32; i += 8)
    tile[ty + i][tx] = w[(size_t)(k0 + ty + i) * N + n0 + tx];
  __syncthreads();
  #pragma unroll
  for (int i = 0; i < 32; i += 8)
    wt[(size_t)(n0 + ty + i) * K + k0 + tx] = f2bf(tile[tx][ty + i]);
}

// ---------------- 256x256x64 8-phase GEMM: C[M][Nld] = A[M][K=768] * Bt[Nld][K=768]^T ----------------
// LDS halves: [buf][A=0/B=1][ks][256 rows x 32 K], 16 KB each, slot-swizzled: slot ^= (row>>1)&3.
// Stage swizzles the GLOBAL source so global_load_lds dest stays linear (both-sides rule).
__device__ __forceinline__ void stage_half(const unsigned short* __restrict__ G, long row0, int col0,
                                           unsigned short* ldsHalf, int t) {
  int r = t >> 2;
  int gslot = (t & 3) ^ ((t >> 3) & 3);
  char* dst = (char*)ldsHalf + ((t >> 6) << 10);  // wave-uniform base; HW adds lane*16
  gload_lds16(G + (row0 + r) * (long)GK + col0 + gslot * 8, (unsigned short*)dst);
  gload_lds16(G + (row0 + 128 + r) * (long)GK + col0 + gslot * 8, (unsigned short*)(dst + 8192));
}
__device__ __forceinline__ bf16x8 frag(const unsigned short* half, int r, int ko) {
  return *(const bf16x8*)((const char*)half + r * 64 + ((((ko >> 3) ^ ((r >> 1) & 3))) << 4));
}

#define MM16(Q) do { \
  acc[(Q)*4+0][0]=__builtin_amdgcn_mfma_f32_16x16x32_bf16(a0,b0,acc[(Q)*4+0][0],0,0,0); \
  acc[(Q)*4+0][1]=__builtin_amdgcn_mfma_f32_16x16x32_bf16(a0,b1,acc[(Q)*4+0][1],0,0,0); \
  acc[(Q)*4+0][2]=__builtin_amdgcn_mfma_f32_16x16x32_bf16(a0,b2,acc[(Q)*4+0][2],0,0,0); \
  acc[(Q)*4+0][3]=__builtin_amdgcn_mfma_f32_16x16x32_bf16(a0,b3,acc[(Q)*4+0][3],0,0,0); \
  acc[(Q)*4+1][0]=__builtin_amdgcn_mfma_f32_16x16x32_bf16(a1,b0,acc[(Q)*4+1][0],0,0,0); \
  acc[(Q)*4+1][1]=__builtin_amdgcn_mfma_f32_16x16x32_bf16(a1,b1,acc[(Q)*4+1][1],0,0,0); \
  acc[(Q)*4+1][2]=__builtin_amdgcn_mfma_f32_16x16x32_bf16(a1,b2,acc[(Q)*4+1][2],0,0,0); \
  acc[(Q)*4+1][3]=__builtin_amdgcn_mfma_f32_16x16x32_bf16(a1,b3,acc[(Q)*4+1][3],0,0,0); \
  acc[(Q)*4+2][0]=__builtin_amdgcn_mfma_f32_16x16x32_bf16(a2,b0,acc[(Q)*4+2][0],0,0,0); \
  acc[(Q)*4+2][1]=__builtin_amdgcn_mfma_f32_16x16x32_bf16(a2,b1,acc[(Q)*4+2][1],0,0,0); \
  acc[(Q)*4+2][2]=__builtin_amdgcn_mfma_f32_16x16x32_bf16(a2,b2,acc[(Q)*4+2][2],0,0,0); \
  acc[(Q)*4+2][3]=__builtin_amdgcn_mfma_f32_16x16x32_bf16(a2,b3,acc[(Q)*4+2][3],0,0,0); \
  acc[(Q)*4+3][0]=__builtin_amdgcn_mfma_f32_16x16x32_bf16(a3,b0,acc[(Q)*4+3][0],0,0,0); \
  acc[(Q)*4+3][1]=__builtin_amdgcn_mfma_f32_16x16x32_bf16(a3,b1,acc[(Q)*4+3][1],0,0,0); \
  acc[(Q)*4+3][2]=__builtin_amdgcn_mfma_f32_16x16x32_bf16(a3,b2,acc[(Q)*4+3][2],0,0,0); \
  acc[(Q)*4+3][3]=__builtin_amdgcn_mfma_f32_16x16x32_bf16(a3,b3,acc[(Q)*4+3][3],0,0,0); \
} while (0)

// One K-tile (4 phases). Stages: p1->A(J+1)ks1, p2->B(J+1)ks1, p3->A(J+2)ks0, p4->B(J+2)ks0.
// Waits: p2 vmcnt(N2?8:0), p4 (if N2) vmcnt(N3?8:4). Ledger-verified, incl. prologue+tail.
#define KTILE(J, BUF, N2, N3) { \
  const unsigned short* Ah0 = &lds[BUF][0][0][0]; \
  const unsigned short* Bh0 = &lds[BUF][1][0][0]; \
  const unsigned short* Ah1 = &lds[BUF][0][1][0]; \
  const unsigned short* Bh1 = &lds[BUF][1][1][0]; \
  bf16x8 a0, a1, a2, a3, b0, b1, b2, b3; \
  /* P1: ks0, mq0 */ \
  a0 = frag(Ah0, ra,      ko); a1 = frag(Ah0, ra + 16, ko); \
  a2 = frag(Ah0, ra + 32, ko); a3 = frag(Ah0, ra + 48, ko); \
  b0 = frag(Bh0, rb,      ko); b1 = frag(Bh0, rb + 16, ko); \
  b2 = frag(Bh0, rb + 32, ko); b3 = frag(Bh0, rb + 48, ko); \
  if (N2) stage_half(A, m0, ((J) + 1) * 64 + 32, &lds[(BUF) ^ 1][0][1][0], t); \
  BARX(); LGKM0(); SB0(); \
  __builtin_amdgcn_s_setprio(1); MM16(0); __builtin_amdgcn_s_setprio(0); BARX(); \
  /* P2: ks0, mq1 */ \
  a0 = frag(Ah0, ra + 64, ko); a1 = frag(Ah0, ra + 80, ko); \
  a2 = frag(Ah0, ra + 96, ko); a3 = frag(Ah0, ra + 112, ko); \
  if (N2) stage_half(Bt, n0, ((J) + 1) * 64 + 32, &lds[(BUF) ^ 1][1][1][0], t); \
  if (N2) { VM8(); } else { VM0(); } \
  BARX(); LGKM0(); SB0(); \
  __builtin_amdgcn_s_setprio(1); MM16(1); __builtin_amdgcn_s_setprio(0); BARX(); \
  /* P3: ks1, mq0 */ \
  a0 = frag(Ah1, ra,      ko); a1 = frag(Ah1, ra + 16, ko); \
  a2 = frag(Ah1, ra + 32, ko); a3 = frag(Ah1, ra + 48, ko); \
  b0 = frag(Bh1, rb,      ko); b1 = frag(Bh1, rb + 16, ko); \
  b2 = frag(Bh1, rb + 32, ko); b3 = frag(Bh1, rb + 48, ko); \
  if (N3) stage_half(A, m0, ((J) + 2) * 64, &lds[BUF][0][0][0], t); \
  BARX(); LGKM0(); SB0(); \
  __builtin_amdgcn_s_setprio(1); MM16(0); __builtin_amdgcn_s_setprio(0); BARX(); \
  /* P4: ks1, mq1 */ \
  a0 = frag(Ah1, ra + 64, ko); a1 = frag(Ah1, ra + 80, ko); \
  a2 = frag(Ah1, ra + 96, ko); a3 = frag(Ah1, ra + 112, ko); \
  if (N3) stage_half(Bt, n0, ((J) + 2) * 64, &lds[BUF][1][0][0], t); \
  if (N2) { if (N3) { VM8(); } else { VM4(); } } \
  BARX(); LGKM0(); SB0(); \
  __builtin_amdgcn_s_setprio(1); MM16(1); __builtin_amdgcn_s_setprio(0); BARX(); \
}

template<int OUTMODE>
__global__ __launch_bounds__(512, 2) void gemm256(const unsigned short* __restrict__ A,
                                                  const unsigned short* __restrict__ Bt,
                                                  void* __restrict__ Cp,
                                                  const float* __restrict__ bias,
                                                  int Nld, int MT) {
  __shared__ unsigned short lds[2][2][2][8192];  // [buf][A/B][ks][256*32], 128 KiB
  int t = threadIdx.x, lane = t & 63, wid = t >> 6;
  int wm = wid >> 2, wn = wid & 3;
  int cpx = (int)gridDim.x >> 3;  // grid % 8 == 0 in all launches
  int wg = ((int)blockIdx.x & 7) * cpx + ((int)blockIdx.x >> 3);
  int mt = wg % MT, nt = wg / MT;
  long m0 = (long)mt * 256, n0 = (long)nt * 256;
  int fl = lane & 15, ko = (lane >> 4) * 8;
  int ra = wm * 128 + fl, rb = wn * 64 + fl;
  f32x4 acc[8][4] = {};
  // prologue: A0ks0,B0ks0,A0ks1,B0ks1,A1ks0,B1ks0 then wait first 2 stage-ops
  stage_half(A,  m0, 0,  &lds[0][0][0][0], t);
  stage_half(Bt, n0, 0,  &lds[0][1][0][0], t);
  stage_half(A,  m0, 32, &lds[0][0][1][0], t);
  stage_half(Bt, n0, 32, &lds[0][1][1][0], t);
  stage_half(A,  m0, 64, &lds[1][0][0][0], t);
  stage_half(Bt, n0, 64, &lds[1][1][0][0], t);
  VM8(); BARX();
  #pragma unroll 1
  for (int jp = 0; jp < 5; ++jp) {
    int j0 = jp * 2;
    KTILE(j0,     0, true, true);
    KTILE(j0 + 1, 1, true, true);
  }
  KTILE(10, 0, true,  false);
  KTILE(11, 1, false, false);
  // epilogue
  int r0 = (lane >> 4) * 4;
  #pragma unroll
  for (int mf = 0; mf < 8; ++mf) {
    #pragma unroll
    for (int nf = 0; nf < 4; ++nf) {
      long row = m0 + wm * 128 + mf * 16 + r0;
      int col = (int)n0 + wn * 64 + nf * 16 + fl;
      if (OUTMODE == 0) {
        unsigned short* C = (unsigned short*)Cp;
        bool doexp = (n0 < 2 * DIM);  // whole 256-tile is q/k or v (1536 % 256 == 0)
        #pragma unroll
        for (int r = 0; r < 4; ++r) {
          float v = acc[mf][nf][r];
          C[(size_t)(row + r) * Nld + col] = f2bf(doexp ? __expf(v) : v);
        }
      } else {
        float* C = (float*)Cp;
        float bb = bias[col];
        #pragma unroll
        for (int r = 0; r < 4; ++r)
          C[(size_t)(row + r) * Nld + col] = acc[mf][nf][r] + bb;
      }
    }
  }
}

// ---------------- context: per (b,h) ctx[c][d] = sum_n ek[n][c] v[n][d] / sum_n ek[n][c] ----------------
__global__ void ctx_kernel(const unsigned short* __restrict__ qkv, unsigned short* __restrict__ ctxT) {
  int bh = blockIdx.x;
  int b = bh / NH, h = bh % NH;
  __shared__ unsigned short Et[64 * 40];
  __shared__ unsigned short Vt[64 * 40];
  __shared__ float denom[64];
  int t = threadIdx.x, lane = t & 63, w = t >> 6;
  if (t < 64) denom[t] = 0.0f;
  int nl = t >> 3, e0 = (t & 7) * 8;
  int ko = (lane >> 4) * 8, fl = lane & 15;
  size_t base = (size_t)b * SEQ * QKVC + (size_t)h * HD;
  float dp[8] = {};
  f32x4 acc[4] = {};
  for (int c0 = 0; c0 < SEQ; c0 += 32) {
    __syncthreads();
    size_t rb = base + (size_t)(c0 + nl) * QKVC;
    uint4 kvec = *(const uint4*)(qkv + rb + DIM + e0);
    uint4 vvec = *(const uint4*)(qkv + rb + 2 * DIM + e0);
    const unsigned short* kp = (const unsigned short*)&kvec;
    const unsigned short* vp = (const unsigned short*)&vvec;
    #pragma unroll
    for (int j = 0; j < 8; ++j) {
      dp[j] += bf2f(kp[j]);
      Et[(e0 + j) * 40 + nl] = kp[j];
      Vt[(e0 + j) * 40 + nl] = vp[j];
    }
    __syncthreads();
    bf16x8 af = *(const bf16x8*)(Et + (w * 16 + fl) * 40 + ko);
    #pragma unroll
    for (int nf = 0; nf < 4; ++nf) {
      bf16x8 bv = *(const bf16x8*)(Vt + (nf * 16 + fl) * 40 + ko);
      acc[nf] = __builtin_amdgcn_mfma_f32_16x16x32_bf16(af, bv, acc[nf], 0, 0, 0);
    }
  }
  #pragma unroll
  for (int j = 0; j < 8; ++j) atomicAdd(&denom[e0 + j], dp[j]);
  __syncthreads();
  int r0 = (lane >> 4) * 4;
  unsigned short* outp = ctxT + (size_t)bh * 4096;
  #pragma unroll
  for (int nf = 0; nf < 4; ++nf)
    #pragma unroll
    for (int r = 0; r < 4; ++r) {
      int c = w * 16 + r0 + r;
      int d = nf * 16 + fl;
      outp[d * 64 + c] = f2bf(acc[nf][r] / denom[c]);
    }
}

// ---------------- PV: out[n][d] = (sum_c eq[n][c] ctx[c][d]) / sum_c eq[n][c] ----------------
__global__ void pv_kernel(const unsigned short* __restrict__ qkv, const unsigned short* __restrict__ ctxT,
                          unsigned short* __restrict__ aout) {
  int bid = blockIdx.x;
  int bh = bid / 49, chunk = bid - bh * 49;
  int b = bh / NH, h = bh % NH;
  int n0 = chunk * 64;
  __shared__ unsigned short P[64 * 80];
  __shared__ unsigned short CT[64 * 80];
  __shared__ float srow[64];
  int t = threadIdx.x, lane = t & 63, w = t >> 6;
  int ko = (lane >> 4) * 8, fl = lane & 15;
  if (t < 64) srow[t] = 0.0f;
  {
    int d = t >> 2, cq = (t & 3) * 16;
    const uint4* src = (const uint4*)(ctxT + (size_t)bh * 4096 + d * 64 + cq);
    *(uint4*)(CT + d * 80 + cq) = src[0];
    *(uint4*)(CT + d * 80 + cq + 8) = src[1];
  }
  __syncthreads();
  {
    int nl = t >> 2, cq = (t & 3) * 16;
    size_t rb = (size_t)(b * SEQ + n0 + nl) * QKVC + h * HD + cq;
    uint4 q0 = *(const uint4*)(qkv + rb);
    uint4 q1 = *(const uint4*)(qkv + rb + 8);
    *(uint4*)(P + nl * 80 + cq) = q0;
    *(uint4*)(P + nl * 80 + cq + 8) = q1;
    const unsigned short* qp0 = (const unsigned short*)&q0;
    const unsigned short* qp1 = (const unsigned short*)&q1;
    float s = 0.0f;
    #pragma unroll
    for (int j = 0; j < 8; ++j) s += bf2f(qp0[j]) + bf2f(qp1[j]);
    atomicAdd(&srow[nl], s);
  }
  __syncthreads();
  f32x4 acc[4] = {};
  #pragma unroll
  for (int kk = 0; kk < 2; ++kk) {
    bf16x8 af = *(const bf16x8*)(P + (w * 16 + fl) * 80 + kk * 32 + ko);
    #pragma unroll
    for (int nf = 0; nf < 4; ++nf) {
      bf16x8 bv = *(const bf16x8*)(CT + (nf * 16 + fl) * 80 + kk * 32 + ko);
      acc[nf] = __builtin_amdgcn_mfma_f32_16x16x32_bf16(af, bv, acc[nf], 0, 0, 0);
    }
  }
  int r0 = (lane >> 4) * 4;
  #pragma unroll
  for (int nf = 0; nf < 4; ++nf)
    #pragma unroll
    for (int r = 0; r < 4; ++r) {
      int nlr = w * 16 + r0 + r;
      int d = nf * 16 + fl;
      float v = acc[nf][r] / srow[nlr];
      aout[(size_t)(b * SEQ + n0 + nlr) * DIM + h * HD + d] = f2bf(v);
    }
}

extern "C" void kernel_launch(void* const* d_in, const int* in_sizes, int n_in,
                              void* d_out, int out_size, void* d_ws, size_t ws_size,
                              hipStream_t stream) {
  const float* x      = (const float*)d_in[0];
  const float* w_qkv  = (const float*)d_in[1];
  const float* w_proj = (const float*)d_in[2];
  const float* b_proj = (const float*)d_in[3];
  char* ws = (char*)d_ws;
  unsigned short* x_bf    = (unsigned short*)(ws);
  unsigned short* wt_qkv  = (unsigned short*)(ws + 154140672);
  unsigned short* wt_proj = (unsigned short*)(ws + 157679616);
  unsigned short* qkv     = (unsigned short*)(ws + 158859264);
  unsigned short* ctxT    = (unsigned short*)(ws + 154140672);  // alias wt_qkv (dead after GEMM1)
  unsigned short* aout    = (unsigned short*)(ws);              // alias x_bf (dead after GEMM1)

  conv_kernel<<<2048, 256, 0, stream>>>(x, x_bf, (long)M_TOT * DIM);
  transp_kernel<<<dim3(QKVC / 32, DIM / 32), dim3(32, 8), 0, stream>>>(w_qkv, wt_qkv, DIM, QKVC);
  transp_kernel<<<dim3(DIM / 32, DIM / 32), dim3(32, 8), 0, stream>>>(w_proj, wt_proj, DIM, DIM);
  gemm256<0><<<(M_TOT / 256) * (QKVC / 256), 512, 0, stream>>>(x_bf, wt_qkv, qkv, nullptr,
                                                               QKVC, M_TOT / 256);
  ctx_kernel<<<BATCH * NH, 256, 0, stream>>>(qkv, ctxT);
  pv_kernel<<<BATCH * NH * (SEQ / 64), 256, 0, stream>>>(qkv, ctxT, aout);
  gemm256<1><<<(M_TOT / 256) * (DIM / 256), 512, 0, stream>>>(aout, wt_proj, (float*)d_out, b_proj,
                                                              DIM, M_TOT / 256);
}

// Round 3
// 810.748 us; speedup vs baseline: 1.3160x; 1.0695x over previous
//
#include <hip/hip_runtime.h>
#include <hip/hip_bf16.h>

typedef __attribute__((ext_vector_type(8))) short bf16x8;
typedef __attribute__((ext_vector_type(4))) float f32x4;

constexpr int BATCH = 32, SEQ = 3136, DIM = 768, NH = 12, HD = 64;
constexpr int M_TOT = BATCH * SEQ;   // 100352
constexpr int QKVC  = 3 * DIM;       // 2304
constexpr int GK    = 768;           // K for both GEMMs

__device__ __forceinline__ float bf2f(unsigned short u) {
  union { unsigned int i; float f; } x; x.i = ((unsigned int)u) << 16; return x.f;
}
__device__ __forceinline__ unsigned short f2bf(float f) {
  union { float f; unsigned int i; } x; x.f = f;
  unsigned int r = x.i + 0x7FFFu + ((x.i >> 16) & 1u);
  return (unsigned short)(r >> 16);
}
__device__ __forceinline__ unsigned int pack2(float lo, float hi) {
  return (unsigned int)f2bf(lo) | ((unsigned int)f2bf(hi) << 16);
}
__device__ __forceinline__ void gload_lds16(const unsigned short* g, unsigned short* l) {
  __builtin_amdgcn_global_load_lds(
      (const __attribute__((address_space(1))) void*)g,
      (__attribute__((address_space(3))) void*)l, 16, 0, 0);
}

#define BARX()  asm volatile("s_barrier" ::: "memory")
#define LGKM0() asm volatile("s_waitcnt lgkmcnt(0)" ::: "memory")
#define VM8()   asm volatile("s_waitcnt vmcnt(8)" ::: "memory")
#define SB0()   __builtin_amdgcn_sched_barrier(0)

// ---------------- fp32 -> bf16 elementwise ----------------
__global__ void conv_kernel(const float* __restrict__ in, unsigned short* __restrict__ out, long n) {
  long i = ((long)blockIdx.x * blockDim.x + threadIdx.x) * 8;
  long stride = (long)gridDim.x * blockDim.x * 8;
  for (; i < n; i += stride) {
    float4 a = *(const float4*)(in + i);
    float4 b = *(const float4*)(in + i + 4);
    uint4 o;
    o.x = pack2(a.x, a.y); o.y = pack2(a.z, a.w);
    o.z = pack2(b.x, b.y); o.w = pack2(b.z, b.w);
    *(uint4*)(out + i) = o;
  }
}

// ---------------- transpose+convert: w[K][N] fp32 -> wt[N][K] bf16 ----------------
__global__ void transp_kernel(const float* __restrict__ w, unsigned short* __restrict__ wt, int K, int N) {
  __shared__ float tile[32][33];
  int n0 = blockIdx.x * 32, k0 = blockIdx.y * 32;
  int tx = threadIdx.x, ty = threadIdx.y;
  #pragma unroll
  for (int i = 0; i < 32; i += 8)
    tile[ty + i][tx] = w[(size_t)(k0 + ty + i) * N + n0 + tx];
  __syncthreads();
  #pragma unroll
  for (int i = 0; i < 32; i += 8)
    wt[(size_t)(n0 + ty + i) * K + k0 + tx] = f2bf(tile[tx][ty + i]);
}

// ---------------- persistent 256x256x64 8-phase GEMM ----------------
__device__ __forceinline__ void stage_half(const unsigned short* __restrict__ G, long row0, int col0,
                                           unsigned short* ldsHalf, int t) {
  int r = t >> 2;
  int gslot = (t & 3) ^ ((t >> 3) & 3);
  char* dst = (char*)ldsHalf + ((t >> 6) << 10);  // wave-uniform base; HW adds lane*16
  gload_lds16(G + (row0 + r) * (long)GK + col0 + gslot * 8, (unsigned short*)dst);
  gload_lds16(G + (row0 + 128 + r) * (long)GK + col0 + gslot * 8, (unsigned short*)(dst + 8192));
}
__device__ __forceinline__ bf16x8 frag(const unsigned short* half, int r, int ko) {
  return *(const bf16x8*)((const char*)half + r * 64 + ((((ko >> 3) ^ ((r >> 1) & 3))) << 4));
}

#define MM16(Q) do { \
  acc[(Q)*4+0][0]=__builtin_amdgcn_mfma_f32_16x16x32_bf16(a0,b0,acc[(Q)*4+0][0],0,0,0); \
  acc[(Q)*4+0][1]=__builtin_amdgcn_mfma_f32_16x16x32_bf16(a0,b1,acc[(Q)*4+0][1],0,0,0); \
  acc[(Q)*4+0][2]=__builtin_amdgcn_mfma_f32_16x16x32_bf16(a0,b2,acc[(Q)*4+0][2],0,0,0); \
  acc[(Q)*4+0][3]=__builtin_amdgcn_mfma_f32_16x16x32_bf16(a0,b3,acc[(Q)*4+0][3],0,0,0); \
  acc[(Q)*4+1][0]=__builtin_amdgcn_mfma_f32_16x16x32_bf16(a1,b0,acc[(Q)*4+1][0],0,0,0); \
  acc[(Q)*4+1][1]=__builtin_amdgcn_mfma_f32_16x16x32_bf16(a1,b1,acc[(Q)*4+1][1],0,0,0); \
  acc[(Q)*4+1][2]=__builtin_amdgcn_mfma_f32_16x16x32_bf16(a1,b2,acc[(Q)*4+1][2],0,0,0); \
  acc[(Q)*4+1][3]=__builtin_amdgcn_mfma_f32_16x16x32_bf16(a1,b3,acc[(Q)*4+1][3],0,0,0); \
  acc[(Q)*4+2][0]=__builtin_amdgcn_mfma_f32_16x16x32_bf16(a2,b0,acc[(Q)*4+2][0],0,0,0); \
  acc[(Q)*4+2][1]=__builtin_amdgcn_mfma_f32_16x16x32_bf16(a2,b1,acc[(Q)*4+2][1],0,0,0); \
  acc[(Q)*4+2][2]=__builtin_amdgcn_mfma_f32_16x16x32_bf16(a2,b2,acc[(Q)*4+2][2],0,0,0); \
  acc[(Q)*4+2][3]=__builtin_amdgcn_mfma_f32_16x16x32_bf16(a2,b3,acc[(Q)*4+2][3],0,0,0); \
  acc[(Q)*4+3][0]=__builtin_amdgcn_mfma_f32_16x16x32_bf16(a3,b0,acc[(Q)*4+3][0],0,0,0); \
  acc[(Q)*4+3][1]=__builtin_amdgcn_mfma_f32_16x16x32_bf16(a3,b1,acc[(Q)*4+3][1],0,0,0); \
  acc[(Q)*4+3][2]=__builtin_amdgcn_mfma_f32_16x16x32_bf16(a3,b2,acc[(Q)*4+3][2],0,0,0); \
  acc[(Q)*4+3][3]=__builtin_amdgcn_mfma_f32_16x16x32_bf16(a3,b3,acc[(Q)*4+3][3],0,0,0); \
} while (0)

// Uniform K-tile: every phase stages; VM8 at P2/P4. Stage targets:
//   P1: A rows MA2, col C2 -> lds[BUF^1][0][1]    P2: B rows NB2, col C2 -> lds[BUF^1][1][1]
//   P3: A rows MA3, col C3 -> lds[BUF][0][0]      P4: B rows NB3, col C3 -> lds[BUF][1][0]
// Ledger (steady state): each VM8 sees 16 outstanding loads, drains to 8 = completes the
// 2 stage_halves read 1-2 phases later. Holds across tile seams (verified incl. prologue).
#define KTILE_U(BUF, MA2, NB2, C2, MA3, NB3, C3) { \
  const unsigned short* Ah0 = &lds[BUF][0][0][0]; \
  const unsigned short* Bh0 = &lds[BUF][1][0][0]; \
  const unsigned short* Ah1 = &lds[BUF][0][1][0]; \
  const unsigned short* Bh1 = &lds[BUF][1][1][0]; \
  bf16x8 a0, a1, a2, a3, b0, b1, b2, b3; \
  /* P1: ks0, mq0 */ \
  a0 = frag(Ah0, ra,      ko); a1 = frag(Ah0, ra + 16, ko); \
  a2 = frag(Ah0, ra + 32, ko); a3 = frag(Ah0, ra + 48, ko); \
  b0 = frag(Bh0, rb,      ko); b1 = frag(Bh0, rb + 16, ko); \
  b2 = frag(Bh0, rb + 32, ko); b3 = frag(Bh0, rb + 48, ko); \
  stage_half(A, MA2, C2, &lds[(BUF) ^ 1][0][1][0], t); \
  BARX(); LGKM0(); SB0(); \
  __builtin_amdgcn_s_setprio(1); MM16(0); __builtin_amdgcn_s_setprio(0); BARX(); \
  /* P2: ks0, mq1 */ \
  a0 = frag(Ah0, ra + 64, ko); a1 = frag(Ah0, ra + 80, ko); \
  a2 = frag(Ah0, ra + 96, ko); a3 = frag(Ah0, ra + 112, ko); \
  stage_half(Bt, NB2, C2, &lds[(BUF) ^ 1][1][1][0], t); \
  VM8(); \
  BARX(); LGKM0(); SB0(); \
  __builtin_amdgcn_s_setprio(1); MM16(1); __builtin_amdgcn_s_setprio(0); BARX(); \
  /* P3: ks1, mq0 */ \
  a0 = frag(Ah1, ra,      ko); a1 = frag(Ah1, ra + 16, ko); \
  a2 = frag(Ah1, ra + 32, ko); a3 = frag(Ah1, ra + 48, ko); \
  b0 = frag(Bh1, rb,      ko); b1 = frag(Bh1, rb + 16, ko); \
  b2 = frag(Bh1, rb + 32, ko); b3 = frag(Bh1, rb + 48, ko); \
  stage_half(A, MA3, C3, &lds[BUF][0][0][0], t); \
  BARX(); LGKM0(); SB0(); \
  __builtin_amdgcn_s_setprio(1); MM16(0); __builtin_amdgcn_s_setprio(0); BARX(); \
  /* P4: ks1, mq1 */ \
  a0 = frag(Ah1, ra + 64, ko); a1 = frag(Ah1, ra + 80, ko); \
  a2 = frag(Ah1, ra + 96, ko); a3 = frag(Ah1, ra + 112, ko); \
  stage_half(Bt, NB3, C3, &lds[BUF][1][0][0], t); \
  VM8(); \
  BARX(); LGKM0(); SB0(); \
  __builtin_amdgcn_s_setprio(1); MM16(1); __builtin_amdgcn_s_setprio(0); BARX(); \
}

template<int OUTMODE, int NT>
__global__ __launch_bounds__(512, 2) void gemm256p(const unsigned short* __restrict__ A,
                                                   const unsigned short* __restrict__ Bt,
                                                   void* __restrict__ Cp,
                                                   const float* __restrict__ bias,
                                                   int Nld, int TPX) {
  __shared__ unsigned short lds[2][2][2][8192];  // [buf][A/B][ks][256*32], 128 KiB
  int t = threadIdx.x, lane = t & 63, wid = t >> 6;
  int wm = wid >> 2, wn = wid & 3;
  int bid = (int)blockIdx.x;
  int xcd = bid & 7, slot = bid >> 3;
  int tau = xcd * TPX + slot;
  int tend = (xcd + 1) * TPX;
  int fl = lane & 15, ko = (lane >> 4) * 8;
  int ra = wm * 128 + fl, rb = wn * 64 + fl;
  f32x4 acc[8][4];
  // prologue: stage tile0 buf0(ks0,ks1) + buf1(ks0)
  {
    long m0 = (long)(tau / NT) * 256, n0 = (long)(tau % NT) * 256;
    stage_half(A,  m0, 0,  &lds[0][0][0][0], t);
    stage_half(Bt, n0, 0,  &lds[0][1][0][0], t);
    stage_half(A,  m0, 32, &lds[0][0][1][0], t);
    stage_half(Bt, n0, 32, &lds[0][1][1][0], t);
    stage_half(A,  m0, 64, &lds[1][0][0][0], t);
    stage_half(Bt, n0, 64, &lds[1][1][0][0], t);
    VM8(); BARX();
  }
  #pragma unroll 1
  for (; tau < tend; tau += 32) {
    long m0 = (long)(tau / NT) * 256, n0 = (long)(tau % NT) * 256;
    int tn = (tau + 32 < tend) ? tau + 32 : tau;
    long m0n = (long)(tn / NT) * 256, n0n = (long)(tn % NT) * 256;
    #pragma unroll
    for (int i = 0; i < 8; ++i)
      #pragma unroll
      for (int j2 = 0; j2 < 4; ++j2) acc[i][j2] = (f32x4){0.f, 0.f, 0.f, 0.f};
    #pragma unroll 1
    for (int j = 0; j < 10; j += 2) {
      KTILE_U(0, m0, n0, j * 64 + 96,  m0, n0, j * 64 + 128);
      KTILE_U(1, m0, n0, j * 64 + 160, m0, n0, j * 64 + 192);
    }
    KTILE_U(0, m0,  n0,  736, m0n, n0n, 0);   // J=10: last cur-tile stage + next buf0-ks0
    KTILE_U(1, m0n, n0n, 32,  m0n, n0n, 64);  // J=11: next buf0-ks1 + buf1-ks0
    // epilogue (no barrier needed: register-only; overlaps in-flight next-tile stages)
    int r0 = (lane >> 4) * 4;
    #pragma unroll
    for (int mf = 0; mf < 8; ++mf) {
      #pragma unroll
      for (int nf = 0; nf < 4; ++nf) {
        long row = m0 + wm * 128 + mf * 16 + r0;
        int col = (int)n0 + wn * 64 + nf * 16 + fl;
        if (OUTMODE == 0) {
          unsigned short* C = (unsigned short*)Cp;
          bool doexp = (n0 < 2 * DIM);
          #pragma unroll
          for (int r = 0; r < 4; ++r) {
            float v = acc[mf][nf][r];
            C[(size_t)(row + r) * Nld + col] = f2bf(doexp ? __expf(v) : v);
          }
        } else {
          float* C = (float*)Cp;
          float bb = bias[col];
          #pragma unroll
          for (int r = 0; r < 4; ++r)
            C[(size_t)(row + r) * Nld + col] = acc[mf][nf][r] + bb;
        }
      }
    }
  }
}

// ---------------- ctx partials: chunk ch of 7, rows [ch*448,(ch+1)*448) ----------------
__global__ void ctx_part(const unsigned short* __restrict__ qkv, float* __restrict__ part,
                         float* __restrict__ dpart) {
  int blk = blockIdx.x;              // 384*7
  int bh = blk / 7, ch = blk - bh * 7;
  int b = bh / NH, h = bh % NH;
  __shared__ unsigned short Et[64 * 40];
  __shared__ unsigned short Vt[64 * 40];
  __shared__ float denom[64];
  int t = threadIdx.x, lane = t & 63, w = t >> 6;
  if (t < 64) denom[t] = 0.0f;
  int nl = t >> 3, e0 = (t & 7) * 8;
  int ko = (lane >> 4) * 8, fl = lane & 15;
  size_t base = (size_t)b * SEQ * QKVC + (size_t)h * HD;
  float dp[8] = {};
  f32x4 acc[4] = {};
  int c0b = ch * 448;
  for (int c0 = c0b; c0 < c0b + 448; c0 += 32) {
    __syncthreads();
    size_t rb = base + (size_t)(c0 + nl) * QKVC;
    uint4 kvec = *(const uint4*)(qkv + rb + DIM + e0);
    uint4 vvec = *(const uint4*)(qkv + rb + 2 * DIM + e0);
    const unsigned short* kp = (const unsigned short*)&kvec;
    const unsigned short* vp = (const unsigned short*)&vvec;
    #pragma unroll
    for (int j = 0; j < 8; ++j) {
      dp[j] += bf2f(kp[j]);
      Et[(e0 + j) * 40 + nl] = kp[j];
      Vt[(e0 + j) * 40 + nl] = vp[j];
    }
    __syncthreads();
    bf16x8 af = *(const bf16x8*)(Et + (w * 16 + fl) * 40 + ko);
    #pragma unroll
    for (int nf = 0; nf < 4; ++nf) {
      bf16x8 bv = *(const bf16x8*)(Vt + (nf * 16 + fl) * 40 + ko);
      acc[nf] = __builtin_amdgcn_mfma_f32_16x16x32_bf16(af, bv, acc[nf], 0, 0, 0);
    }
  }
  #pragma unroll
  for (int j = 0; j < 8; ++j) atomicAdd(&denom[e0 + j], dp[j]);
  __syncthreads();
  int r0 = (lane >> 4) * 4;
  float* pp = part + (size_t)blk * 4096;
  #pragma unroll
  for (int nf = 0; nf < 4; ++nf)
    #pragma unroll
    for (int r = 0; r < 4; ++r) {
      int c = w * 16 + r0 + r;
      int d = nf * 16 + fl;
      pp[d * 64 + c] = acc[nf][r];
    }
  if (t < 64) dpart[blk * 64 + t] = denom[t];
}

// ---------------- ctx reduce over 7 chunks -> ctxT[bh][d*64+c] bf16 ----------------
__global__ void ctx_reduce(const float* __restrict__ part, const float* __restrict__ dpart,
                           unsigned short* __restrict__ ctxT) {
  int bh = blockIdx.x, t = threadIdx.x;
  const float* pp = part + (size_t)bh * 7 * 4096;
  const float* dd = dpart + (size_t)bh * 7 * 64;
  #pragma unroll
  for (int i = 0; i < 16; ++i) {
    int idx = i * 256 + t;
    float s = 0.f, ds = 0.f;
    #pragma unroll
    for (int c = 0; c < 7; ++c) {
      s += pp[c * 4096 + idx];
      ds += dd[c * 64 + (idx & 63)];
    }
    ctxT[(size_t)bh * 4096 + idx] = f2bf(s / ds);
  }
}

// ---------------- PV: out[n][d] = (sum_c eq[n][c] ctx[c][d]) / sum_c eq[n][c] ----------------
__global__ void pv_kernel(const unsigned short* __restrict__ qkv, const unsigned short* __restrict__ ctxT,
                          unsigned short* __restrict__ aout) {
  int bid = blockIdx.x;
  int bh = bid / 49, chunk = bid - bh * 49;
  int b = bh / NH, h = bh % NH;
  int n0 = chunk * 64;
  __shared__ unsigned short P[64 * 80];
  __shared__ unsigned short CT[64 * 80];
  __shared__ float srow[64];
  int t = threadIdx.x, lane = t & 63, w = t >> 6;
  int ko = (lane >> 4) * 8, fl = lane & 15;
  if (t < 64) srow[t] = 0.0f;
  {
    int d = t >> 2, cq = (t & 3) * 16;
    const uint4* src = (const uint4*)(ctxT + (size_t)bh * 4096 + d * 64 + cq);
    *(uint4*)(CT + d * 80 + cq) = src[0];
    *(uint4*)(CT + d * 80 + cq + 8) = src[1];
  }
  __syncthreads();
  {
    int nl = t >> 2, cq = (t & 3) * 16;
    size_t rb = (size_t)(b * SEQ + n0 + nl) * QKVC + h * HD + cq;
    uint4 q0 = *(const uint4*)(qkv + rb);
    uint4 q1 = *(const uint4*)(qkv + rb + 8);
    *(uint4*)(P + nl * 80 + cq) = q0;
    *(uint4*)(P + nl * 80 + cq + 8) = q1;
    const unsigned short* qp0 = (const unsigned short*)&q0;
    const unsigned short* qp1 = (const unsigned short*)&q1;
    float s = 0.0f;
    #pragma unroll
    for (int j = 0; j < 8; ++j) s += bf2f(qp0[j]) + bf2f(qp1[j]);
    atomicAdd(&srow[nl], s);
  }
  __syncthreads();
  f32x4 acc[4] = {};
  #pragma unroll
  for (int kk = 0; kk < 2; ++kk) {
    bf16x8 af = *(const bf16x8*)(P + (w * 16 + fl) * 80 + kk * 32 + ko);
    #pragma unroll
    for (int nf = 0; nf < 4; ++nf) {
      bf16x8 bv = *(const bf16x8*)(CT + (nf * 16 + fl) * 80 + kk * 32 + ko);
      acc[nf] = __builtin_amdgcn_mfma_f32_16x16x32_bf16(af, bv, acc[nf], 0, 0, 0);
    }
  }
  int r0 = (lane >> 4) * 4;
  #pragma unroll
  for (int nf = 0; nf < 4; ++nf)
    #pragma unroll
    for (int r = 0; r < 4; ++r) {
      int nlr = w * 16 + r0 + r;
      int d = nf * 16 + fl;
      float v = acc[nf][r] / srow[nlr];
      aout[(size_t)(b * SEQ + n0 + nlr) * DIM + h * HD + d] = f2bf(v);
    }
}

extern "C" void kernel_launch(void* const* d_in, const int* in_sizes, int n_in,
                              void* d_out, int out_size, void* d_ws, size_t ws_size,
                              hipStream_t stream) {
  const float* x      = (const float*)d_in[0];
  const float* w_qkv  = (const float*)d_in[1];
  const float* w_proj = (const float*)d_in[2];
  const float* b_proj = (const float*)d_in[3];
  char* ws = (char*)d_ws;
  unsigned short* x_bf    = (unsigned short*)(ws);
  unsigned short* wt_qkv  = (unsigned short*)(ws + 154140672);
  unsigned short* wt_proj = (unsigned short*)(ws + 157679616);
  unsigned short* qkv     = (unsigned short*)(ws + 158859264);
  unsigned short* ctxT    = (unsigned short*)(ws + 154140672);  // alias wt_qkv (dead after GEMM1)
  float* part  = (float*)(ws);                 // alias x_bf region (dead after GEMM1), 44.0 MB
  float* dpart = (float*)(ws + 44040192);      // 688 KB
  unsigned short* aout = (unsigned short*)(ws);  // alias x_bf/part (partials dead after reduce)

  conv_kernel<<<2048, 256, 0, stream>>>(x, x_bf, (long)M_TOT * DIM);
  transp_kernel<<<dim3(QKVC / 32, DIM / 32), dim3(32, 8), 0, stream>>>(w_qkv, wt_qkv, DIM, QKVC);
  transp_kernel<<<dim3(DIM / 32, DIM / 32), dim3(32, 8), 0, stream>>>(w_proj, wt_proj, DIM, DIM);
  gemm256p<0, 9><<<256, 512, 0, stream>>>(x_bf, wt_qkv, qkv, nullptr, QKVC, 441);
  ctx_part<<<BATCH * NH * 7, 256, 0, stream>>>(qkv, part, dpart);
  ctx_reduce<<<BATCH * NH, 256, 0, stream>>>(part, dpart, ctxT);
  pv_kernel<<<BATCH * NH * (SEQ / 64), 256, 0, stream>>>(qkv, ctxT, aout);
  gemm256p<1, 3><<<256, 512, 0, stream>>>(aout, wt_proj, (float*)d_out, b_proj, DIM, 147);
}